// Round 3
// baseline (433.569 us; speedup 1.0000x reference)
//
#include <hip/hip_runtime.h>
#include <hip/hip_bf16.h>

// DensePermutation: P21 = softmax_j(-||feat2_i - feat1_j|| / 0.1)
// feat1, feat2: [8192][128] f32.  out: [8192][8192] f32.
//
// Plan:
//  K0: split f32 -> bf16 hi/lo planes (Markidis split) + row sq-norms.
//  K1: MFMA GEMM pass (3-term bf16 split = fp32-grade cross) -> per-(row, jtile)
//      online-softmax partials (m, l) in ws.
//  K2: reduce 64 partials/row -> row max, 1/rowsum.
//  K3: MFMA GEMM pass again, fused epilogue writes P (the only 256MB traffic).

#define N 8192
#define D 128

typedef short s16x8 __attribute__((ext_vector_type(8)));
typedef unsigned short u16x8 __attribute__((ext_vector_type(8)));
typedef float f32x4 __attribute__((ext_vector_type(4)));

// ws layout (bytes)
#define OFF_F1H (0u)
#define OFF_F1L (2u << 20)
#define OFF_F2H (4u << 20)
#define OFF_F2L (6u << 20)
#define OFF_SQ1 (8u << 20)
#define OFF_SQ2 ((8u << 20) + (32u << 10))
#define OFF_MX  ((8u << 20) + (64u << 10))
#define OFF_RL  ((8u << 20) + (96u << 10))
#define OFF_PM  ((8u << 20) + (128u << 10))
#define OFF_PL  ((10u << 20) + (128u << 10))

__device__ inline unsigned short f2bf(float x) {
    unsigned u = __builtin_bit_cast(unsigned, x);
    return (unsigned short)((u + 0x7fffu + ((u >> 16) & 1u)) >> 16);
}
__device__ inline float bf2f(unsigned short b) {
    return __builtin_bit_cast(float, (unsigned)b << 16);
}

// ---------------- K0: split + row norms ----------------
__global__ __launch_bounds__(256) void k_split(
        const float* __restrict__ f1, const float* __restrict__ f2,
        unsigned short* __restrict__ f1h, unsigned short* __restrict__ f1l,
        unsigned short* __restrict__ f2h, unsigned short* __restrict__ f2l,
        float* __restrict__ sq1, float* __restrict__ sq2) {
    const int wid = threadIdx.x >> 6, lane = threadIdx.x & 63;
    const int row = blockIdx.x * 4 + wid;
    const float* src = blockIdx.y ? f2 : f1;
    unsigned short* dh = blockIdx.y ? f2h : f1h;
    unsigned short* dl = blockIdx.y ? f2l : f1l;
    float* sq = blockIdx.y ? sq2 : sq1;

    float2 x = ((const float2*)src)[row * 64 + lane];
    unsigned short h0 = f2bf(x.x), h1 = f2bf(x.y);
    unsigned short l0 = f2bf(x.x - bf2f(h0)), l1 = f2bf(x.y - bf2f(h1));
    ((ushort2*)dh)[row * 64 + lane] = make_ushort2(h0, h1);
    ((ushort2*)dl)[row * 64 + lane] = make_ushort2(l0, l1);
    float s = x.x * x.x + x.y * x.y;
    #pragma unroll
    for (int m = 32; m; m >>= 1) s += __shfl_xor(s, m);
    if (lane == 0) sq[row] = s;
}

// ---------------- K1/K3: tiled MFMA GEMM core ----------------
// 128x128 tile, 4 waves (2x2, each 64x64), BK=64 (2 k-halves), 64KB LDS.
// LDS tiles (each [128 rows][64 bf16], XOR-swizzled): Ahi@0 Alo@16K Bhi@32K Blo@48K.
template <int PASS>
__global__ __launch_bounds__(256) void k_gemm(
        const unsigned short* __restrict__ f1h, const unsigned short* __restrict__ f1l,
        const unsigned short* __restrict__ f2h, const unsigned short* __restrict__ f2l,
        const float* __restrict__ sq1, const float* __restrict__ sq2,
        const float* __restrict__ mx, const float* __restrict__ rlv,
        float* __restrict__ pm, float* __restrict__ pl,
        float* __restrict__ out) {
    __shared__ __align__(16) char lds[65536];
    const int t = threadIdx.x;
    const int jt = blockIdx.x, it = blockIdx.y;
    const int i0 = it * 128, j0 = jt * 128;
    const int w = t >> 6, lane = t & 63;
    const int wr = w >> 1, wc = w & 1;
    const int lr = lane & 15, kg = lane >> 4;

    f32x4 acc[4][4];
    #pragma unroll
    for (int a = 0; a < 4; ++a)
        #pragma unroll
        for (int b = 0; b < 4; ++b) acc[a][b] = (f32x4){0.f, 0.f, 0.f, 0.f};

    for (int kh = 0; kh < 2; ++kh) {
        if (kh) __syncthreads();
        // stage: 4 tiles x 16KB; 256 threads x 4 chunks of 16B per tile
        #pragma unroll
        for (int c = 0; c < 4; ++c) {
            int chunk = c * 256 + t;          // 0..1023
            int row = chunk >> 3;             // 0..127
            int cc = chunk & 7;               // 16B chunk in row
            int g = kh * 8 + cc;              // 16B chunk in global row (of 16)
            int ga = (i0 + row) * 128 + g * 8;
            int gb = (j0 + row) * 128 + g * 8;
            int loff = (row * 128 + cc * 16) ^ ((row & 7) << 4);
            *(u16x8*)(lds + 0 * 16384 + loff) = *(const u16x8*)(f2h + ga);
            *(u16x8*)(lds + 1 * 16384 + loff) = *(const u16x8*)(f2l + ga);
            *(u16x8*)(lds + 2 * 16384 + loff) = *(const u16x8*)(f1h + gb);
            *(u16x8*)(lds + 3 * 16384 + loff) = *(const u16x8*)(f1l + gb);
        }
        __syncthreads();
        #pragma unroll
        for (int ks = 0; ks < 2; ++ks) {
            s16x8 ah[4], al[4], bh[4], bl[4];
            #pragma unroll
            for (int mi = 0; mi < 4; ++mi) {
                int row = wr * 64 + mi * 16 + lr;
                int off = (row * 128 + (ks * 32 + kg * 8) * 2) ^ ((row & 7) << 4);
                ah[mi] = *(const s16x8*)(lds + 0 * 16384 + off);
                al[mi] = *(const s16x8*)(lds + 1 * 16384 + off);
            }
            #pragma unroll
            for (int ni = 0; ni < 4; ++ni) {
                int row = wc * 64 + ni * 16 + lr;
                int off = (row * 128 + (ks * 32 + kg * 8) * 2) ^ ((row & 7) << 4);
                bh[ni] = *(const s16x8*)(lds + 2 * 16384 + off);
                bl[ni] = *(const s16x8*)(lds + 3 * 16384 + off);
            }
            #pragma unroll
            for (int mi = 0; mi < 4; ++mi)
                #pragma unroll
                for (int ni = 0; ni < 4; ++ni) {
                    acc[mi][ni] = __builtin_amdgcn_mfma_f32_16x16x32_bf16(ah[mi], bh[ni], acc[mi][ni], 0, 0, 0);
                    acc[mi][ni] = __builtin_amdgcn_mfma_f32_16x16x32_bf16(ah[mi], bl[ni], acc[mi][ni], 0, 0, 0);
                    acc[mi][ni] = __builtin_amdgcn_mfma_f32_16x16x32_bf16(al[mi], bh[ni], acc[mi][ni], 0, 0, 0);
                }
        }
    }
    __syncthreads();
    // ---- epilogue: repurpose LDS for per-tile tables ----
    float* sq2t = (float*)lds;            // [128]
    float* sq1t = (float*)(lds + 512);    // [128]
    float* mxt  = (float*)(lds + 1024);   // [128] (pass 2)
    float* rlt  = (float*)(lds + 1536);   // [128] (pass 2)
    float* pm2  = (float*)(lds + 2048);   // [128][2] (pass 1)
    float* pl2  = (float*)(lds + 3072);   // [128][2] (pass 1)
    if (t < 128) {
        sq2t[t] = sq2[i0 + t];
        if (PASS == 2) { mxt[t] = mx[i0 + t]; rlt[t] = rlv[i0 + t]; }
    } else {
        sq1t[t - 128] = sq1[j0 + t - 128];
    }
    __syncthreads();

    if (PASS == 2) {
        #pragma unroll
        for (int mi = 0; mi < 4; ++mi)
            #pragma unroll
            for (int rg = 0; rg < 4; ++rg) {
                int row_l = wr * 64 + mi * 16 + kg * 4 + rg;
                float s2 = sq2t[row_l], m_ = mxt[row_l], r_ = rlt[row_l];
                #pragma unroll
                for (int ni = 0; ni < 4; ++ni) {
                    int col_l = wc * 64 + ni * 16 + lr;
                    float sd = s2 + sq1t[col_l] - 2.0f * acc[mi][ni][rg];
                    float dist = sqrtf(fmaxf(sd, 0.0f));
                    float p = __expf(-10.0f * dist - m_) * r_;
                    out[(i0 + row_l) * N + j0 + col_l] = p;
                }
            }
    } else {
        #pragma unroll
        for (int mi = 0; mi < 4; ++mi)
            #pragma unroll
            for (int rg = 0; rg < 4; ++rg) {
                int row_l = wr * 64 + mi * 16 + kg * 4 + rg;
                float s2 = sq2t[row_l];
                float lv[4];
                float rm = -1e30f, rs = 0.0f;
                #pragma unroll
                for (int ni = 0; ni < 4; ++ni) {
                    int col_l = wc * 64 + ni * 16 + lr;
                    float sd = s2 + sq1t[col_l] - 2.0f * acc[mi][ni][rg];
                    lv[ni] = -10.0f * sqrtf(fmaxf(sd, 0.0f));
                    rm = fmaxf(rm, lv[ni]);
                }
                #pragma unroll
                for (int ni = 0; ni < 4; ++ni) rs += __expf(lv[ni] - rm);
                // combine (m,l) across the 16 lanes of this row group
                #pragma unroll
                for (int msk = 1; msk < 16; msk <<= 1) {
                    float om = __shfl_xor(rm, msk);
                    float os = __shfl_xor(rs, msk);
                    float nm = fmaxf(rm, om);
                    rs = rs * __expf(rm - nm) + os * __expf(om - nm);
                    rm = nm;
                }
                if (lr == 0) { pm2[row_l * 2 + wc] = rm; pl2[row_l * 2 + wc] = rs; }
            }
        __syncthreads();
        if (t < 128) {
            float m0 = pm2[t * 2 + 0], m1 = pm2[t * 2 + 1];
            float s0 = pl2[t * 2 + 0], s1 = pl2[t * 2 + 1];
            float nm = fmaxf(m0, m1);
            float ns = s0 * __expf(m0 - nm) + s1 * __expf(m1 - nm);
            pm[(i0 + t) * 64 + jt] = nm;
            pl[(i0 + t) * 64 + jt] = ns;
        }
    }
}

// ---------------- K2: reduce partials per row ----------------
__global__ __launch_bounds__(256) void k_reduce(
        const float* __restrict__ pm, const float* __restrict__ pl,
        float* __restrict__ mx, float* __restrict__ rlv) {
    const int w = threadIdx.x >> 6, lane = threadIdx.x & 63;
    const int row = blockIdx.x * 4 + w;
    float m = pm[row * 64 + lane];
    float s = pl[row * 64 + lane];
    #pragma unroll
    for (int msk = 1; msk < 64; msk <<= 1) {
        float om = __shfl_xor(m, msk);
        float os = __shfl_xor(s, msk);
        float nm = fmaxf(m, om);
        s = s * __expf(m - nm) + os * __expf(om - nm);
        m = nm;
    }
    if (lane == 0) { mx[row] = m; rlv[row] = 1.0f / s; }
}

extern "C" void kernel_launch(void* const* d_in, const int* in_sizes, int n_in,
                              void* d_out, int out_size, void* d_ws, size_t ws_size,
                              hipStream_t stream) {
    const float* f1 = (const float*)d_in[0];
    const float* f2 = (const float*)d_in[1];
    float* out = (float*)d_out;
    char* ws = (char*)d_ws;

    unsigned short* f1h = (unsigned short*)(ws + OFF_F1H);
    unsigned short* f1l = (unsigned short*)(ws + OFF_F1L);
    unsigned short* f2h = (unsigned short*)(ws + OFF_F2H);
    unsigned short* f2l = (unsigned short*)(ws + OFF_F2L);
    float* sq1 = (float*)(ws + OFF_SQ1);
    float* sq2 = (float*)(ws + OFF_SQ2);
    float* mx  = (float*)(ws + OFF_MX);
    float* rlv = (float*)(ws + OFF_RL);
    float* pm  = (float*)(ws + OFF_PM);
    float* pl  = (float*)(ws + OFF_PL);

    k_split<<<dim3(N / 4, 2), 256, 0, stream>>>(f1, f2, f1h, f1l, f2h, f2l, sq1, sq2);
    k_gemm<1><<<dim3(N / 128, N / 128), 256, 0, stream>>>(f1h, f1l, f2h, f2l, sq1, sq2, mx, rlv, pm, pl, out);
    k_reduce<<<N / 4, 256, 0, stream>>>(pm, pl, mx, rlv);
    k_gemm<2><<<dim3(N / 128, N / 128), 256, 0, stream>>>(f1h, f1l, f2h, f2l, sq1, sq2, mx, rlv, pm, pl, out);
}